// Round 1
// baseline (118.516 us; speedup 1.0000x reference)
//
#include <hip/hip_runtime.h>

#define NN 2048
#define INF_ 512
#define OUTF 256
#define HH 4
#define NHH 64

// -------- K1: g = h @ W  (f32), fused el/er epilogue --------
__global__ __launch_bounds__(256) void k_gemm_el_er(
    const float* __restrict__ hin, const float* __restrict__ W,
    const float* __restrict__ aw, float* __restrict__ g,
    float* __restrict__ el, float* __restrict__ er) {
  __shared__ float hs[8][512];
  const int tid = threadIdx.x;
  const int r0 = blockIdx.x * 8;

  const float4* hsrc = (const float4*)(hin + r0 * 512);
  float4* hdst = (float4*)&hs[0][0];
#pragma unroll
  for (int k = 0; k < 4; ++k) hdst[tid + k * 256] = hsrc[tid + k * 256];
  __syncthreads();

  float acc[8] = {0.f, 0.f, 0.f, 0.f, 0.f, 0.f, 0.f, 0.f};
#pragma unroll 8
  for (int k = 0; k < 512; ++k) {
    float wk = W[k * 256 + tid];
#pragma unroll
    for (int r = 0; r < 8; ++r) acc[r] += hs[r][k] * wk;
  }

#pragma unroll
  for (int r = 0; r < 8; ++r) g[(r0 + r) * 256 + tid] = acc[r];

  const int lane = tid & 63;
  const int w = tid >> 6;  // = head h
  const float asrc = aw[lane];
  const float adst = aw[64 + lane];
#pragma unroll
  for (int r = 0; r < 8; ++r) {
    float e1 = acc[r] * asrc;
    float e2 = acc[r] * adst;
#pragma unroll
    for (int m = 1; m < 64; m <<= 1) {
      e1 += __shfl_xor(e1, m);
      e2 += __shfl_xor(e2, m);
    }
    if (lane == 0) {
      el[(r0 + r) * 4 + w] = e1;
      er[(r0 + r) * 4 + w] = e2;
    }
  }
}

// -------- K3: per-row Z1[h], Z2 (store reciprocals) --------
__global__ __launch_bounds__(256) void k_row_z(
    const float* __restrict__ adj, const float* __restrict__ s,
    const float* __restrict__ el, const float* __restrict__ er,
    float* __restrict__ rZ1, float* __restrict__ rZ2) {
  const int i = blockIdx.x;
  const int tid = threadIdx.x;

  float4 e4 = *(const float4*)(el + i * 4);
  float eli[4] = {e4.x, e4.y, e4.z, e4.w};

  float z1[4] = {0.f, 0.f, 0.f, 0.f};
  float z2 = 0.f;

  const float4* a4 = (const float4*)(adj + (size_t)i * NN);
  const float4* s4 = (const float4*)(s + (size_t)i * NN);
#pragma unroll
  for (int b = 0; b < 2; ++b) {
    int v = tid + b * 256;  // float4 index, 0..511
    float4 av = a4[v];
    float4 sv = s4[v];
    float aa[4] = {av.x, av.y, av.z, av.w};
    float ss[4] = {sv.x, sv.y, sv.z, sv.w};
#pragma unroll
    for (int u = 0; u < 4; ++u) {
      int j = v * 4 + u;
      bool nb = (aa[u] != 0.f);
      float es = __expf(ss[u]);
      z2 += nb ? es : 0.f;
      float4 r4 = *(const float4*)(er + j * 4);
      float erv[4] = {r4.x, r4.y, r4.z, r4.w};
#pragma unroll
      for (int h = 0; h < 4; ++h) {
        float x = eli[h] + erv[h];
        x = (x > 0.f) ? x : 0.2f * x;  // leaky relu
        float ex = __expf(x);
        z1[h] += nb ? ex : 0.f;
      }
    }
  }

#pragma unroll
  for (int m = 1; m < 64; m <<= 1) {
    z2 += __shfl_xor(z2, m);
#pragma unroll
    for (int h = 0; h < 4; ++h) z1[h] += __shfl_xor(z1[h], m);
  }

  __shared__ float wr[4][5];
  const int lane = tid & 63;
  const int w = tid >> 6;
  if (lane == 0) {
    wr[w][0] = z1[0]; wr[w][1] = z1[1]; wr[w][2] = z1[2]; wr[w][3] = z1[3];
    wr[w][4] = z2;
  }
  __syncthreads();
  if (tid < 5) {
    float sum = wr[0][tid] + wr[1][tid] + wr[2][tid] + wr[3][tid];
    if (tid < 4) rZ1[i * 4 + tid] = 1.f / sum;
    else rZ2[i] = 1.f / sum;
  }
}

// -------- K4: main fused pass --------
// grid 256: blockIdx -> (ib = bx>>1 : 16-row block, jh = bx&1 : j half)
// block 512 threads (8 waves). Phase A: build c tile in LDS; Phase B: FMA contraction.
__global__ __launch_bounds__(512) void k_attn_main(
    const float* __restrict__ adj, const float* __restrict__ s,
    const float* __restrict__ g, const float* __restrict__ el,
    const float* __restrict__ er, const float* __restrict__ rZ1,
    const float* __restrict__ rZ2, float* __restrict__ U,
    float* __restrict__ Z3p) {
  __shared__ float cs[64 * 68];  // [jj][h*16 + ii], padded stride 68

  const int tid = threadIdx.x;
  const int w = tid >> 6;     // wave 0..7
  const int lane = tid & 63;
  const int ib = blockIdx.x >> 1;
  const int jh = blockIdx.x & 1;
  const int i0 = ib * 16;
  const int j0b = jh * 1024;

  const int rowA = i0 + w;        // phase-A row q=0
  const int rowB = i0 + w + 8;    // phase-A row q=1

  float4 t4;
  t4 = *(const float4*)(el + rowA * 4);  float elA[4] = {t4.x, t4.y, t4.z, t4.w};
  t4 = *(const float4*)(el + rowB * 4);  float elB[4] = {t4.x, t4.y, t4.z, t4.w};
  t4 = *(const float4*)(rZ1 + rowA * 4); float z1A[4] = {t4.x, t4.y, t4.z, t4.w};
  t4 = *(const float4*)(rZ1 + rowB * 4); float z1B[4] = {t4.x, t4.y, t4.z, t4.w};
  const float z2A = rZ2[rowA];
  const float z2B = rZ2[rowB];

  float z3a[8] = {0.f, 0.f, 0.f, 0.f, 0.f, 0.f, 0.f, 0.f};  // [q*4+h]
  float acc[8] = {0.f, 0.f, 0.f, 0.f, 0.f, 0.f, 0.f, 0.f};

  const int hB = w & 3;          // phase-B head
  const int ihalf = w >> 2;      // phase-B row half
  const int coff = hB * 16 + ihalf * 8;

  for (int jt = 0; jt < 16; ++jt) {
    const int j0 = j0b + jt * 64;
    const int j = j0 + lane;

    // ---- phase A ----
    float4 r4 = *(const float4*)(er + j * 4);
    float erv[4] = {r4.x, r4.y, r4.z, r4.w};
    {
      float a = adj[(size_t)rowA * NN + j];
      float sv = s[(size_t)rowA * NN + j];
      bool nb = (a != 0.f);
      float sp = nb ? __expf(sv) * z2A : 0.f;
#pragma unroll
      for (int h = 0; h < 4; ++h) {
        float x = elA[h] + erv[h];
        x = (x > 0.f) ? x : 0.2f * x;
        float tt = nb ? __expf(x) * z1A[h] + sp : 0.f;
        float c = __expf(tt);
        cs[lane * 68 + h * 16 + w] = c;
        z3a[h] += c;
      }
    }
    {
      float a = adj[(size_t)rowB * NN + j];
      float sv = s[(size_t)rowB * NN + j];
      bool nb = (a != 0.f);
      float sp = nb ? __expf(sv) * z2B : 0.f;
#pragma unroll
      for (int h = 0; h < 4; ++h) {
        float x = elB[h] + erv[h];
        x = (x > 0.f) ? x : 0.2f * x;
        float tt = nb ? __expf(x) * z1B[h] + sp : 0.f;
        float c = __expf(tt);
        cs[lane * 68 + h * 16 + w + 8] = c;
        z3a[4 + h] += c;
      }
    }
    __syncthreads();

    // ---- phase B ----
    const float* gp = g + (size_t)j0 * 256 + hB * 64 + lane;
#pragma unroll 8
    for (int jj = 0; jj < 64; ++jj) {
      float gv = gp[(size_t)jj * 256];
      float4 c4a = *(const float4*)&cs[jj * 68 + coff];
      float4 c4b = *(const float4*)&cs[jj * 68 + coff + 4];
      acc[0] += c4a.x * gv; acc[1] += c4a.y * gv;
      acc[2] += c4a.z * gv; acc[3] += c4a.w * gv;
      acc[4] += c4b.x * gv; acc[5] += c4b.y * gv;
      acc[6] += c4b.z * gv; acc[7] += c4b.w * gv;
    }
    __syncthreads();
  }

  // reduce Z3 partials over lanes (jj) per wave
#pragma unroll
  for (int m = 1; m < 64; m <<= 1) {
#pragma unroll
    for (int k = 0; k < 8; ++k) z3a[k] += __shfl_xor(z3a[k], m);
  }
  if (lane == 0) {
    float4 zA = make_float4(z3a[0], z3a[1], z3a[2], z3a[3]);
    float4 zB = make_float4(z3a[4], z3a[5], z3a[6], z3a[7]);
    *(float4*)(Z3p + jh * (NN * 4) + rowA * 4) = zA;
    *(float4*)(Z3p + jh * (NN * 4) + rowB * 4) = zB;
  }

  // write U partials
  float* up = U + (size_t)jh * (NN * OUTF) + (size_t)(i0 + ihalf * 8) * 256 + hB * 64 + lane;
#pragma unroll
  for (int k = 0; k < 8; ++k) up[(size_t)k * 256] = acc[k];
}

// -------- K5: combine j-halves, divide by Z3 --------
__global__ __launch_bounds__(256) void k_finalize(
    const float* __restrict__ U, const float* __restrict__ Z3p,
    float* __restrict__ out) {
  const int i = blockIdx.x;
  const int c = threadIdx.x;
  const int h = c >> 6;
  float u = U[(size_t)i * 256 + c] + U[(size_t)NN * OUTF + (size_t)i * 256 + c];
  float z = Z3p[i * 4 + h] + Z3p[NN * 4 + i * 4 + h];
  out[(size_t)i * 256 + c] = u / z;
}

extern "C" void kernel_launch(void* const* d_in, const int* in_sizes, int n_in,
                              void* d_out, int out_size, void* d_ws, size_t ws_size,
                              hipStream_t stream) {
  const float* hin = (const float*)d_in[0];
  const float* adj = (const float*)d_in[1];
  const float* s   = (const float*)d_in[2];
  const float* W   = (const float*)d_in[3];
  const float* aw  = (const float*)d_in[4];
  float* out = (float*)d_out;

  float* ws = (float*)d_ws;
  float* g   = ws;                 // 524288
  float* el  = g + 524288;         // 8192
  float* er  = el + 8192;          // 8192
  float* rZ1 = er + 8192;          // 8192
  float* rZ2 = rZ1 + 8192;         // 2048
  float* U   = rZ2 + 2048;         // 2 * 524288
  float* Z3p = U + 1048576;        // 2 * 8192

  k_gemm_el_er<<<256, 256, 0, stream>>>(hin, W, aw, g, el, er);
  k_row_z<<<2048, 256, 0, stream>>>(adj, s, el, er, rZ1, rZ2);
  k_attn_main<<<256, 512, 0, stream>>>(adj, s, g, el, er, rZ1, rZ2, U, Z3p);
  k_finalize<<<2048, 256, 0, stream>>>(U, Z3p, out);
}

// Round 2
// 93.706 us; speedup vs baseline: 1.2648x; 1.2648x over previous
//
#include <hip/hip_runtime.h>

#define NN 2048

typedef __attribute__((ext_vector_type(8))) short bf16x8;
typedef __attribute__((ext_vector_type(4))) float f32x4;

__device__ inline ushort f2bf(float x) {
  union { float f; unsigned u; } v; v.f = x;
  unsigned r = v.u + 0x7fffu + ((v.u >> 16) & 1u);
  return (ushort)(r >> 16);
}

// -------- K1: g = h @ W (f32) + el/er epilogue. grid 512, 4 rows/block --------
__global__ __launch_bounds__(256) void k_gemm(
    const float* __restrict__ hin, const float* __restrict__ W,
    const float* __restrict__ aw, float* __restrict__ g,
    float* __restrict__ el, float* __restrict__ er) {
  __shared__ float hs[4][512];
  const int tid = threadIdx.x;
  const int r0 = blockIdx.x * 4;

  const float4* hsrc = (const float4*)(hin + r0 * 512);
  float4* hdst = (float4*)&hs[0][0];
  hdst[tid] = hsrc[tid];
  hdst[tid + 256] = hsrc[tid + 256];
  __syncthreads();

  float acc[4] = {0.f, 0.f, 0.f, 0.f};
#pragma unroll 8
  for (int k = 0; k < 512; ++k) {
    float wk = W[k * 256 + tid];
#pragma unroll
    for (int r = 0; r < 4; ++r) acc[r] += hs[r][k] * wk;
  }
#pragma unroll
  for (int r = 0; r < 4; ++r) g[(r0 + r) * 256 + tid] = acc[r];

  const int lane = tid & 63;
  const int w = tid >> 6;  // head
  const float asrc = aw[lane];
  const float adst = aw[64 + lane];
#pragma unroll
  for (int r = 0; r < 4; ++r) {
    float e1 = acc[r] * asrc;
    float e2 = acc[r] * adst;
#pragma unroll
    for (int m = 1; m < 64; m <<= 1) {
      e1 += __shfl_xor(e1, m);
      e2 += __shfl_xor(e2, m);
    }
    if (lane == 0) {
      el[(r0 + r) * 4 + w] = e1;
      er[(r0 + r) * 4 + w] = e2;
    }
  }
}

// -------- K2: gT (bf16 transpose of g) + exp tables. grid 136 --------
__global__ __launch_bounds__(256) void k_prep(
    const float* __restrict__ g, const float* __restrict__ el,
    const float* __restrict__ er, ushort* __restrict__ gT,
    float* __restrict__ Eel, float* __restrict__ Fel,
    float* __restrict__ Eer_jh, float* __restrict__ Fer_jh,
    float* __restrict__ Eer_hj, float* __restrict__ Fer_hj) {
  const int bx = blockIdx.x;
  const int t = threadIdx.x;
  if (bx < 128) {
    __shared__ float ts[64][65];
    const int r0 = (bx >> 2) * 64;
    const int c0 = (bx & 3) * 64;
    const int tr = t >> 6;   // 0..3
    const int tc = t & 63;
#pragma unroll
    for (int i = 0; i < 16; ++i)
      ts[tr + i * 4][tc] = g[(size_t)(r0 + tr + i * 4) * 256 + c0 + tc];
    __syncthreads();
#pragma unroll
    for (int i = 0; i < 16; ++i) {
      float v = ts[tc][tr + i * 4];
      gT[(size_t)(c0 + tr + i * 4) * NN + r0 + tc] = f2bf(v);
    }
  } else {
    const int idx = (bx - 128) * 256 + t;  // 0..2047
    float4 e4 = *(const float4*)(el + idx * 4);
    float4 r4 = *(const float4*)(er + idx * 4);
    float el_[4] = {e4.x, e4.y, e4.z, e4.w};
    float er_[4] = {r4.x, r4.y, r4.z, r4.w};
    float eel[4], fel[4], eer[4], fer[4];
#pragma unroll
    for (int h = 0; h < 4; ++h) {
      eel[h] = __expf(el_[h]);
      fel[h] = __expf(0.2f * el_[h]);
      eer[h] = __expf(er_[h]);
      fer[h] = __expf(0.2f * er_[h]);
    }
    *(float4*)(Eel + idx * 4) = make_float4(eel[0], eel[1], eel[2], eel[3]);
    *(float4*)(Fel + idx * 4) = make_float4(fel[0], fel[1], fel[2], fel[3]);
    *(float4*)(Eer_jh + idx * 4) = make_float4(eer[0], eer[1], eer[2], eer[3]);
    *(float4*)(Fer_jh + idx * 4) = make_float4(fer[0], fer[1], fer[2], fer[3]);
#pragma unroll
    for (int h = 0; h < 4; ++h) {
      Eer_hj[h * NN + idx] = eer[h];
      Fer_hj[h * NN + idx] = fer[h];
    }
  }
}

// -------- K3: per-row Z1[h], Z2 via tables. grid 512, wave=row, no LDS --------
__global__ __launch_bounds__(256) void k_rowz(
    const float* __restrict__ adj, const float* __restrict__ s,
    const float* __restrict__ Eel, const float* __restrict__ Fel,
    const float* __restrict__ Eer_jh, const float* __restrict__ Fer_jh,
    float* __restrict__ rZ1, float* __restrict__ rZ2) {
  const int tid = threadIdx.x;
  const int lane = tid & 63;
  const int w = tid >> 6;
  const int row = blockIdx.x * 4 + w;

  float4 e4 = *(const float4*)(Eel + row * 4);
  float4 f4 = *(const float4*)(Fel + row * 4);
  const float eel[4] = {e4.x, e4.y, e4.z, e4.w};
  const float fel[4] = {f4.x, f4.y, f4.z, f4.w};

  float z1[4] = {0.f, 0.f, 0.f, 0.f};
  float z2 = 0.f;

  const float* ap = adj + (size_t)row * NN;
  const float* sp = s + (size_t)row * NN;

#pragma unroll 4
  for (int u = 0; u < 32; ++u) {
    const int j = u * 64 + lane;
    float a = ap[j];
    float sv = sp[j];
    float4 eer4 = *(const float4*)(Eer_jh + j * 4);
    float4 fer4 = *(const float4*)(Fer_jh + j * 4);
    bool nb = (a != 0.f);
    z2 += nb ? __expf(sv) : 0.f;
    float eerv[4] = {eer4.x, eer4.y, eer4.z, eer4.w};
    float ferv[4] = {fer4.x, fer4.y, fer4.z, fer4.w};
#pragma unroll
    for (int h = 0; h < 4; ++h) {
      float p = eel[h] * eerv[h];
      float q = fel[h] * ferv[h];
      float E = (p > 1.f) ? p : q;
      z1[h] += nb ? E : 0.f;
    }
  }

#pragma unroll
  for (int m = 1; m < 64; m <<= 1) {
    z2 += __shfl_xor(z2, m);
#pragma unroll
    for (int h = 0; h < 4; ++h) z1[h] += __shfl_xor(z1[h], m);
  }
  if (lane == 0) {
#pragma unroll
    for (int h = 0; h < 4; ++h) rZ1[row * 4 + h] = 1.f / z1[h];
    rZ2[row] = 1.f / z2;
  }
}

// -------- K4: fused coefficient + MFMA contraction. grid 1024, no LDS --------
// block = 4 waves, wave = head. lane: il = lane&15 (row), kg = lane>>4 (k-group)
__global__ __launch_bounds__(256, 4) void k_attn(
    const float* __restrict__ adj, const float* __restrict__ s,
    const ushort* __restrict__ gT,
    const float* __restrict__ Eel, const float* __restrict__ Fel,
    const float* __restrict__ Eer_hj, const float* __restrict__ Fer_hj,
    const float* __restrict__ rZ1, const float* __restrict__ rZ2,
    float* __restrict__ U, float* __restrict__ Z3p) {
  const int tid = threadIdx.x;
  const int h = tid >> 6;
  const int lane = tid & 63;
  const int ib = blockIdx.x >> 3;
  const int jc = blockIdx.x & 7;
  const int i0 = ib * 16;
  const int jb0 = jc * 256;

  const int il = lane & 15;
  const int kg = lane >> 4;
  const int row = i0 + il;

  const float eel = Eel[row * 4 + h];
  const float fel = Fel[row * 4 + h];
  const float rz1 = rZ1[row * 4 + h];
  const float rz2 = rZ2[row];

  f32x4 acc0 = {0.f, 0.f, 0.f, 0.f};
  f32x4 acc1 = {0.f, 0.f, 0.f, 0.f};
  f32x4 acc2 = {0.f, 0.f, 0.f, 0.f};
  f32x4 acc3 = {0.f, 0.f, 0.f, 0.f};
  float z3 = 0.f;

  const float* adjp = adj + (size_t)row * NN + jb0 + kg * 8;
  const float* sp_ = s + (size_t)row * NN + jb0 + kg * 8;
  const float* eerp = Eer_hj + h * NN + jb0 + kg * 8;
  const float* ferp = Fer_hj + h * NN + jb0 + kg * 8;
  const ushort* bp = gT + (size_t)(h * 64 + il) * NN + jb0 + kg * 8;

  for (int ks = 0; ks < 8; ++ks) {
    const int o = ks * 32;
    float4 a0 = *(const float4*)(adjp + o);
    float4 a1 = *(const float4*)(adjp + o + 4);
    float4 s0 = *(const float4*)(sp_ + o);
    float4 s1 = *(const float4*)(sp_ + o + 4);
    float4 e0 = *(const float4*)(eerp + o);
    float4 e1 = *(const float4*)(eerp + o + 4);
    float4 f0 = *(const float4*)(ferp + o);
    float4 f1 = *(const float4*)(ferp + o + 4);
    bf16x8 B0 = *(const bf16x8*)(bp + o);
    bf16x8 B1 = *(const bf16x8*)(bp + 16 * NN + o);
    bf16x8 B2 = *(const bf16x8*)(bp + 32 * NN + o);
    bf16x8 B3 = *(const bf16x8*)(bp + 48 * NN + o);

    float av[8] = {a0.x, a0.y, a0.z, a0.w, a1.x, a1.y, a1.z, a1.w};
    float sv[8] = {s0.x, s0.y, s0.z, s0.w, s1.x, s1.y, s1.z, s1.w};
    float ev[8] = {e0.x, e0.y, e0.z, e0.w, e1.x, e1.y, e1.z, e1.w};
    float fv[8] = {f0.x, f0.y, f0.z, f0.w, f1.x, f1.y, f1.z, f1.w};

    bf16x8 A;
#pragma unroll
    for (int e = 0; e < 8; ++e) {
      bool nb = (av[e] != 0.f);
      float spv = __expf(sv[e]) * rz2;
      float p = eel * ev[e];
      float q = fel * fv[e];
      float E = (p > 1.f) ? p : q;
      float tt = nb ? (E * rz1 + spv) : 0.f;
      float c = __expf(tt);
      z3 += c;
      A[e] = (short)f2bf(c);
    }
    acc0 = __builtin_amdgcn_mfma_f32_16x16x32_bf16(A, B0, acc0, 0, 0, 0);
    acc1 = __builtin_amdgcn_mfma_f32_16x16x32_bf16(A, B1, acc1, 0, 0, 0);
    acc2 = __builtin_amdgcn_mfma_f32_16x16x32_bf16(A, B2, acc2, 0, 0, 0);
    acc3 = __builtin_amdgcn_mfma_f32_16x16x32_bf16(A, B3, acc3, 0, 0, 0);
  }

  // Z3[i,h] for this chunk: sum over kg groups
  z3 += __shfl_xor(z3, 16);
  z3 += __shfl_xor(z3, 32);
  if (lane < 16)
    Z3p[jc * (NN * 4) + (i0 + lane) * 4 + h] = z3;

  // U partial: C/D layout col=lane&15, row=(lane>>4)*4+q
  float* up = U + (size_t)jc * (NN * 256);
#pragma unroll
  for (int q = 0; q < 4; ++q) {
    const size_t ro = (size_t)(i0 + kg * 4 + q) * 256 + h * 64 + il;
    up[ro] = acc0[q];
    up[ro + 16] = acc1[q];
    up[ro + 32] = acc2[q];
    up[ro + 48] = acc3[q];
  }
}

// -------- K5: combine 8 j-chunk partials, divide by Z3 --------
__global__ __launch_bounds__(256) void k_final(
    const float* __restrict__ U, const float* __restrict__ Z3p,
    float* __restrict__ out) {
  const int i = blockIdx.x;
  const int c = threadIdx.x;
  const int h = c >> 6;
  float u = 0.f, z = 0.f;
#pragma unroll
  for (int p = 0; p < 8; ++p) {
    u += U[(size_t)p * (NN * 256) + (size_t)i * 256 + c];
    z += Z3p[p * (NN * 4) + i * 4 + h];
  }
  out[(size_t)i * 256 + c] = u / z;
}

extern "C" void kernel_launch(void* const* d_in, const int* in_sizes, int n_in,
                              void* d_out, int out_size, void* d_ws, size_t ws_size,
                              hipStream_t stream) {
  const float* hin = (const float*)d_in[0];
  const float* adj = (const float*)d_in[1];
  const float* s = (const float*)d_in[2];
  const float* W = (const float*)d_in[3];
  const float* aw = (const float*)d_in[4];
  float* out = (float*)d_out;

  float* ws = (float*)d_ws;
  float* g      = ws;             // 524288
  float* el     = ws + 524288;    // 8192
  float* er     = ws + 532480;    // 8192
  float* Eel    = ws + 540672;    // 8192
  float* Fel    = ws + 548864;    // 8192
  float* Eer_jh = ws + 557056;    // 8192
  float* Fer_jh = ws + 565248;    // 8192
  float* Eer_hj = ws + 573440;    // 8192
  float* Fer_hj = ws + 581632;    // 8192
  float* rZ1    = ws + 589824;    // 8192
  float* rZ2    = ws + 598016;    // 2048
  float* Z3p    = ws + 600064;    // 65536
  float* U      = ws + 665600;    // 4194304
  ushort* gT    = (ushort*)(ws + 4859904);  // 524288 ushorts

  k_gemm<<<512, 256, 0, stream>>>(hin, W, aw, g, el, er);
  k_prep<<<136, 256, 0, stream>>>(g, el, er, gT, Eel, Fel, Eer_jh, Fer_jh, Eer_hj, Fer_hj);
  k_rowz<<<512, 256, 0, stream>>>(adj, s, Eel, Fel, Eer_jh, Fer_jh, rZ1, rZ2);
  k_attn<<<1024, 256, 0, stream>>>(adj, s, gT, Eel, Fel, Eer_hj, Fer_hj, rZ1, rZ2, U, Z3p);
  k_final<<<2048, 256, 0, stream>>>(U, Z3p, out);
}

// Round 4
// 69.599 us; speedup vs baseline: 1.7028x; 1.3464x over previous
//
#include <hip/hip_runtime.h>

#define NN 2048
#define KK 512

typedef __attribute__((ext_vector_type(8))) short bf16x8;
typedef __attribute__((ext_vector_type(4))) float f32x4;

__device__ inline ushort f2bf(float x) {  // RNE f32->bf16
  union { float f; unsigned u; } v; v.f = x;
  unsigned r = v.u + 0x7fffu + ((v.u >> 16) & 1u);
  return (ushort)(r >> 16);
}

// -------- K1: g = h @ W (f32) + el/er epilogue. grid 512, 4 rows/block -----
// (verbatim from R2 — proven)
__global__ __launch_bounds__(256) void k_gemm(
    const float* __restrict__ hin, const float* __restrict__ W,
    const float* __restrict__ aw, float* __restrict__ g,
    float* __restrict__ el, float* __restrict__ er) {
  __shared__ float hs[4][512];
  const int tid = threadIdx.x;
  const int r0 = blockIdx.x * 4;

  const float4* hsrc = (const float4*)(hin + r0 * 512);
  float4* hdst = (float4*)&hs[0][0];
  hdst[tid] = hsrc[tid];
  hdst[tid + 256] = hsrc[tid + 256];
  __syncthreads();

  float acc[4] = {0.f, 0.f, 0.f, 0.f};
#pragma unroll 8
  for (int k = 0; k < 512; ++k) {
    float wk = W[k * 256 + tid];
#pragma unroll
    for (int r = 0; r < 4; ++r) acc[r] += hs[r][k] * wk;
  }
#pragma unroll
  for (int r = 0; r < 4; ++r) g[(r0 + r) * 256 + tid] = acc[r];

  const int lane = tid & 63;
  const int w = tid >> 6;  // head
  const float asrc = aw[lane];
  const float adst = aw[64 + lane];
#pragma unroll
  for (int r = 0; r < 4; ++r) {
    float e1 = acc[r] * asrc;
    float e2 = acc[r] * adst;
#pragma unroll
    for (int m = 1; m < 64; m <<= 1) {
      e1 += __shfl_xor(e1, m);
      e2 += __shfl_xor(e2, m);
    }
    if (lane == 0) {
      el[(r0 + r) * 4 + w] = e1;
      er[(r0 + r) * 4 + w] = e2;
    }
  }
}

// -------- K2: gTb (tiled bf16: [j/8][f][8]) + exp tables. grid 136 --------
// (R2's k_prep with only the transpose WRITE retargeted to the tiled layout)
__global__ __launch_bounds__(256) void k_prep(
    const float* __restrict__ g, const float* __restrict__ el,
    const float* __restrict__ er, ushort* __restrict__ gTb,
    float* __restrict__ Eel, float* __restrict__ Fel,
    float* __restrict__ Eer_jh, float* __restrict__ Fer_jh,
    float* __restrict__ Eer_hj, float* __restrict__ Fer_hj) {
  const int bx = blockIdx.x;
  const int t = threadIdx.x;
  if (bx < 128) {
    __shared__ float ts[64][65];
    const int r0 = (bx >> 2) * 64;   // j block
    const int c0 = (bx & 3) * 64;    // f block
    const int tr = t >> 6;           // 0..3
    const int tc = t & 63;
#pragma unroll
    for (int i = 0; i < 16; ++i)
      ts[tr + i * 4][tc] = g[(size_t)(r0 + tr + i * 4) * 256 + c0 + tc];
    __syncthreads();
#pragma unroll
    for (int i = 0; i < 16; ++i) {
      float v = ts[tc][tr + i * 4];          // = g[r0+tc][c0+tr+i*4]
      const int j = r0 + tc;
      const int f = c0 + tr + i * 4;
      gTb[(size_t)(j >> 3) * 2048 + f * 8 + (j & 7)] = f2bf(v);
    }
  } else {
    const int idx = (bx - 128) * 256 + t;  // 0..2047
    float4 e4 = *(const float4*)(el + idx * 4);
    float4 r4 = *(const float4*)(er + idx * 4);
    float el_[4] = {e4.x, e4.y, e4.z, e4.w};
    float er_[4] = {r4.x, r4.y, r4.z, r4.w};
    float eel[4], fel[4], eer[4], fer[4];
#pragma unroll
    for (int h = 0; h < 4; ++h) {
      eel[h] = __expf(el_[h]);
      fel[h] = __expf(0.2f * el_[h]);
      eer[h] = __expf(er_[h]);
      fer[h] = __expf(0.2f * er_[h]);
    }
    *(float4*)(Eel + idx * 4) = make_float4(eel[0], eel[1], eel[2], eel[3]);
    *(float4*)(Fel + idx * 4) = make_float4(fel[0], fel[1], fel[2], fel[3]);
    *(float4*)(Eer_jh + idx * 4) = make_float4(eer[0], eer[1], eer[2], eer[3]);
    *(float4*)(Fer_jh + idx * 4) = make_float4(fer[0], fer[1], fer[2], fer[3]);
#pragma unroll
    for (int h = 0; h < 4; ++h) {
      Eer_hj[h * NN + idx] = eer[h];
      Fer_hj[h * NN + idx] = fer[h];
    }
  }
}

// -------- K3: Z1[h], Z2 + adjacency bitmask. grid 2048 (block = row) -------
__global__ __launch_bounds__(256) void k_rowz(
    const float* __restrict__ adj, const float* __restrict__ s,
    const float* __restrict__ Eel, const float* __restrict__ Fel,
    const float* __restrict__ Eer_jh, const float* __restrict__ Fer_jh,
    float* __restrict__ rZ1, float* __restrict__ rZ2,
    unsigned long long* __restrict__ maskb) {
  const int row = blockIdx.x;
  const int tid = threadIdx.x;
  const int wq = tid >> 6;
  const int lane = tid & 63;

  float4 e4 = *(const float4*)(Eel + row * 4);
  float4 f4 = *(const float4*)(Fel + row * 4);
  const float eel[4] = {e4.x, e4.y, e4.z, e4.w};
  const float fel[4] = {f4.x, f4.y, f4.z, f4.w};

  float z1[4] = {0.f, 0.f, 0.f, 0.f};
  float z2 = 0.f;

  const float* ap = adj + (size_t)row * NN + wq * 512;
  const float* sp = s + (size_t)row * NN + wq * 512;

#pragma unroll
  for (int it = 0; it < 8; ++it) {
    const int j = it * 64 + lane;
    float a = ap[j];
    float sv = sp[j];
    bool nb = (a != 0.f);
    unsigned long long m = __ballot(nb);
    if (lane == 0) maskb[row * 32 + wq * 8 + it] = m;
    const int jg = wq * 512 + j;
    float4 eer4 = *(const float4*)(Eer_jh + jg * 4);
    float4 fer4 = *(const float4*)(Fer_jh + jg * 4);
    z2 += nb ? __expf(sv) : 0.f;
    float ev[4] = {eer4.x, eer4.y, eer4.z, eer4.w};
    float fv[4] = {fer4.x, fer4.y, fer4.z, fer4.w};
#pragma unroll
    for (int h = 0; h < 4; ++h) {
      float p = eel[h] * ev[h];
      float q = fel[h] * fv[h];
      float E = (p > 1.f) ? p : q;
      z1[h] += nb ? E : 0.f;
    }
  }

#pragma unroll
  for (int m = 1; m < 64; m <<= 1) {
    z2 += __shfl_xor(z2, m);
#pragma unroll
    for (int h = 0; h < 4; ++h) z1[h] += __shfl_xor(z1[h], m);
  }

  __shared__ float wr[4][5];
  if (lane == 0) {
    wr[wq][0] = z1[0]; wr[wq][1] = z1[1]; wr[wq][2] = z1[2]; wr[wq][3] = z1[3];
    wr[wq][4] = z2;
  }
  __syncthreads();
  if (tid < 5) {
    float sum = wr[0][tid] + wr[1][tid] + wr[2][tid] + wr[3][tid];
    if (tid < 4) rZ1[row * 4 + tid] = 1.f / sum;
    else rZ2[row] = 1.f / sum;
  }
}

// -------- K4: coefficient + MFMA contraction. grid 2048 -------------------
// wave = head h; lane: il = lane&15 (i-row), kg = lane>>4 (k-group)
__global__ __launch_bounds__(256, 8) void k_attn(
    const float* __restrict__ s, const unsigned long long* __restrict__ maskb,
    const ushort* __restrict__ gTb,
    const float* __restrict__ Eel, const float* __restrict__ Fel,
    const float* __restrict__ Eer_hj, const float* __restrict__ Fer_hj,
    const float* __restrict__ rZ1, const float* __restrict__ rZ2,
    _Float16* __restrict__ U, float* __restrict__ Z3p) {
  const int tid = threadIdx.x;
  const int h = tid >> 6;
  const int lane = tid & 63;
  const int il = lane & 15;
  const int kg = lane >> 4;
  const int ib = blockIdx.x >> 4;
  const int jc = blockIdx.x & 15;
  const int i0 = ib * 16;
  const int jb0 = jc * 128;
  const int row = i0 + il;

  const float eel = Eel[row * 4 + h];
  const float fel = Fel[row * 4 + h];
  const float rz1 = rZ1[row * 4 + h];
  const float rz2 = rZ2[row];

  const unsigned long long* mp = maskb + row * 32 + jc * 2;
  const unsigned long long m0 = mp[0];
  const unsigned long long m1 = mp[1];

  f32x4 acc[4];
#pragma unroll
  for (int nt = 0; nt < 4; ++nt) acc[nt] = (f32x4){0.f, 0.f, 0.f, 0.f};
  float z3 = 0.f;

  const float* sp = s + (size_t)row * NN + jb0 + kg * 8;
  const float* eerp = Eer_hj + h * NN + jb0 + kg * 8;
  const float* ferp = Fer_hj + h * NN + jb0 + kg * 8;
  const ushort* bp = gTb + (size_t)(jc * 16 + kg) * 2048 + (h * 64 + il) * 8;

#pragma unroll
  for (int ks = 0; ks < 4; ++ks) {
    const int o = ks * 32;
    unsigned long long w = (ks & 2) ? m1 : m0;
    unsigned byte_ = (unsigned)(w >> ((ks & 1) * 32 + kg * 8)) & 0xffu;

    bf16x8 A;
#pragma unroll
    for (int gp = 0; gp < 2; ++gp) {
      float4 s4 = *(const float4*)(sp + o + gp * 4);
      float4 ee4 = *(const float4*)(eerp + o + gp * 4);
      float4 fe4 = *(const float4*)(ferp + o + gp * 4);
      float sv[4] = {s4.x, s4.y, s4.z, s4.w};
      float ev[4] = {ee4.x, ee4.y, ee4.z, ee4.w};
      float fv[4] = {fe4.x, fe4.y, fe4.z, fe4.w};
#pragma unroll
      for (int e = 0; e < 4; ++e) {
        bool nb = (byte_ >> (gp * 4 + e)) & 1u;
        float spv = __expf(sv[e]) * rz2;
        float p = eel * ev[e];
        float q = fel * fv[e];
        float E = (p > 1.f) ? p : q;
        float tt = nb ? (E * rz1 + spv) : 0.f;
        float c = __expf(tt);
        z3 += c;
        A[gp * 4 + e] = (short)f2bf(c);
      }
    }

    const ushort* bks = bp + (size_t)(ks * 4) * 2048;
    acc[0] = __builtin_amdgcn_mfma_f32_16x16x32_bf16(A, *(const bf16x8*)(bks), acc[0], 0, 0, 0);
    acc[1] = __builtin_amdgcn_mfma_f32_16x16x32_bf16(A, *(const bf16x8*)(bks + 128), acc[1], 0, 0, 0);
    acc[2] = __builtin_amdgcn_mfma_f32_16x16x32_bf16(A, *(const bf16x8*)(bks + 256), acc[2], 0, 0, 0);
    acc[3] = __builtin_amdgcn_mfma_f32_16x16x32_bf16(A, *(const bf16x8*)(bks + 384), acc[3], 0, 0, 0);
  }

  z3 += __shfl_xor(z3, 16);
  z3 += __shfl_xor(z3, 32);
  if (lane < 16)
    Z3p[jc * (NN * 4) + (i0 + lane) * 4 + h] = z3;

  _Float16* up = U + (size_t)jc * (NN * 256) + (size_t)i0 * 256 + h * 64 + il;
#pragma unroll
  for (int nt = 0; nt < 4; ++nt)
#pragma unroll
    for (int q = 0; q < 4; ++q)
      up[(size_t)(kg * 4 + q) * 256 + nt * 16] = (_Float16)acc[nt][q];
}

// -------- K5: combine 16 partials, divide by Z3 --------
__global__ __launch_bounds__(256) void k_final(
    const _Float16* __restrict__ U, const float* __restrict__ Z3p,
    float* __restrict__ out) {
  const int i = blockIdx.x;
  const int c = threadIdx.x;
  const int h = c >> 6;
  float u = 0.f, z = 0.f;
#pragma unroll
  for (int p = 0; p < 16; ++p) {
    u += (float)U[(size_t)p * (NN * 256) + (size_t)i * 256 + c];
    z += Z3p[p * (NN * 4) + i * 4 + h];
  }
  out[(size_t)i * 256 + c] = u / z;
}

extern "C" void kernel_launch(void* const* d_in, const int* in_sizes, int n_in,
                              void* d_out, int out_size, void* d_ws, size_t ws_size,
                              hipStream_t stream) {
  const float* hin = (const float*)d_in[0];
  const float* adj = (const float*)d_in[1];
  const float* s = (const float*)d_in[2];
  const float* W = (const float*)d_in[3];
  const float* aw = (const float*)d_in[4];
  float* out = (float*)d_out;

  float* ws = (float*)d_ws;
  // U (f16, written K4) overlaps g (f32, dead after K2) — saves 2 MB peak.
  _Float16* U   = (_Float16*)ws;            // 8388608 f16 = 4194304 f32-slots
  float* g      = ws;                       // 524288 (inside U region; g dead before K4)
  float* el     = ws + 4194304;             // 8192
  float* er     = ws + 4202496;             // 8192
  float* Eel    = ws + 4210688;             // 8192
  float* Fel    = ws + 4218880;             // 8192
  float* Eer_jh = ws + 4227072;             // 8192
  float* Fer_jh = ws + 4235264;             // 8192
  float* Eer_hj = ws + 4243456;             // 8192
  float* Fer_hj = ws + 4251648;             // 8192
  float* rZ1    = ws + 4259840;             // 8192
  float* rZ2    = ws + 4268032;             // 2048
  float* Z3p    = ws + 4270080;             // 131072
  unsigned long long* maskb = (unsigned long long*)(ws + 4401152);  // 65536 u64
  ushort* gTb   = (ushort*)(ws + 4532224);  // 524288 ushorts -> ends 4794368 f32 (19.2 MB)

  k_gemm<<<512, 256, 0, stream>>>(hin, W, aw, g, el, er);
  k_prep<<<136, 256, 0, stream>>>(g, el, er, gTb, Eel, Fel, Eer_jh, Fer_jh, Eer_hj, Fer_hj);
  k_rowz<<<2048, 256, 0, stream>>>(adj, s, Eel, Fel, Eer_jh, Fer_jh, rZ1, rZ2, maskb);
  k_attn<<<2048, 256, 0, stream>>>(s, maskb, gTb, Eel, Fel, Eer_hj, Fer_hj, rZ1, rZ2, U, Z3p);
  k_final<<<2048, 256, 0, stream>>>(U, Z3p, out);
}